// Round 3
// baseline (531.568 us; speedup 1.0000x reference)
//
#include <hip/hip_runtime.h>

#define AS1 __attribute__((address_space(1)))
#define AS3 __attribute__((address_space(3)))

typedef __attribute__((ext_vector_type(8))) short short8;        // 8 bf16 raw (4 VGPRs) — MFMA A/B frag
typedef __attribute__((ext_vector_type(4))) float floatx4;       // MFMA C/D frag
typedef __attribute__((ext_vector_type(8))) unsigned short u16x8;
typedef __attribute__((ext_vector_type(4))) float f32x4;

#define M_DIM 8192   // B*S = 4*2048
#define K_DIM 4096   // IN_F
#define N_DIM 4096   // OUT_F
#define NB    512    // blocks along in/out feature dims
// BLK = 8

// fp32 -> bf16 raw bits, round-to-nearest-even (finite inputs only).
static __device__ __forceinline__ unsigned short f32_to_bf16(float f) {
  union { float f; unsigned int u; } v;
  v.f = f;
  return (unsigned short)((v.u + 0x7FFFu + ((v.u >> 16) & 1u)) >> 16);
}

// ---------------------------------------------------------------------------
// Convert x fp32 -> bf16 raw. 8 elements (32B read, 16B write) per thread.
// ---------------------------------------------------------------------------
__global__ __launch_bounds__(256) void convert_x_kernel(
    const float* __restrict__ x,            // (8192*4096) fp32
    unsigned short* __restrict__ Xb)        // (8192*4096) bf16 raw
{
  const size_t t = (size_t)blockIdx.x * 256 + threadIdx.x;  // 0 .. 4194303
  const f32x4 a = *reinterpret_cast<const f32x4*>(x + t * 8);
  const f32x4 b = *reinterpret_cast<const f32x4*>(x + t * 8 + 4);
  union { u16x8 v; unsigned short s[8]; } o;
#pragma unroll
  for (int u = 0; u < 4; ++u) {
    o.s[u]     = f32_to_bf16(a[u]);
    o.s[u + 4] = f32_to_bf16(b[u]);
  }
  *reinterpret_cast<u16x8*>(Xb + t * 8) = o.v;
}

// ---------------------------------------------------------------------------
// Expand block-circulant params c(512,512,8) fp32 into dense bf16 W (N x K,
// row-major): W[o][k] = c[o>>3][k>>3][((o&7)-(k&7)) & 7].
// One thread per 8-element (16B-out) chunk: tid = o*512 + i.
// ---------------------------------------------------------------------------
__global__ __launch_bounds__(256) void expand_w_kernel(
    const float* __restrict__ c,            // (512,512,8) fp32
    unsigned short* __restrict__ W)         // (4096,4096) bf16 raw
{
  const int tid = blockIdx.x * 256 + threadIdx.x;  // 0 .. 4096*512-1
  const int o = tid >> 9;     // output feature row 0..4095
  const int i = tid & 511;    // input block
  const int n = o >> 3;
  const int t = o & 7;

  const float* src = c + ((size_t)(n * NB + i) << 3);
  float raw[8];
  *reinterpret_cast<f32x4*>(raw)     = *reinterpret_cast<const f32x4*>(src);
  *reinterpret_cast<f32x4*>(raw + 4) = *reinterpret_cast<const f32x4*>(src + 4);
  union { u16x8 v; unsigned short s[8]; } outv;
#pragma unroll
  for (int u = 0; u < 8; ++u) outv.s[u] = f32_to_bf16(raw[(t - u) & 7]);
  *reinterpret_cast<u16x8*>(W + (size_t)o * K_DIM + i * 8) = outv.v;
}

// ---------------------------------------------------------------------------
// m97-structure bf16 GEMM, C = A(M,K) * B(N,K)^T + bias, bf16 in, fp32 out.
// 128x128 tile, BK=32, 256 threads = 4 waves in 2x2, each wave 4x4 frags of
// 16x16x32 MFMA. Staging via global_load_lds width=16 (wave-uniform base +
// lane*16 — LDS layout matches chunk order exactly, no padding).
// ---------------------------------------------------------------------------
__global__ __launch_bounds__(256) void gemm_bt_kernel(
    const unsigned short* __restrict__ A,    // (8192,4096) bf16 = Xb
    const unsigned short* __restrict__ Bm,   // (4096,4096) bf16 = W
    const float* __restrict__ bias,          // (4096) fp32
    float* __restrict__ C)                   // (8192,4096) fp32 out
{
  __shared__ alignas(16) unsigned short As[128 * 32];
  __shared__ alignas(16) unsigned short Bs[128 * 32];

  const int tid  = threadIdx.x;
  const int lane = tid & 63;
  const int wave = tid >> 6;
  const int wm   = wave >> 1;   // wave row in 2x2
  const int wn   = wave & 1;    // wave col in 2x2
  const int m0   = blockIdx.y * 128;
  const int n0   = blockIdx.x * 128;

  const int quad = lane >> 4;   // 0..3
  const int l15  = lane & 15;

  floatx4 acc[4][4];
#pragma unroll
  for (int i = 0; i < 4; ++i)
#pragma unroll
    for (int j = 0; j < 4; ++j) acc[i][j] = (floatx4){0.f, 0.f, 0.f, 0.f};

  for (int k0 = 0; k0 < K_DIM; k0 += 32) {
    // ---- stage A(128x32) and B(128x32) tiles: 512 chunks of 16B each ----
#pragma unroll
    for (int j = 0; j < 2; ++j) {
      const int chunk = j * 256 + wave * 64 + lane;  // 16B chunk id, lane-linear
      const int row   = chunk >> 2;                  // tile row (4 chunks = 64B/row)
      const int kc    = (chunk & 3) << 3;            // k offset within tile
      const unsigned short* ga = A  + (size_t)(m0 + row) * K_DIM + (k0 + kc);
      const unsigned short* gb = Bm + (size_t)(n0 + row) * K_DIM + (k0 + kc);
      // wave-uniform LDS base (elements); HW adds lane*16B
      unsigned short* la = As + (j * 256 + wave * 64) * 8;
      unsigned short* lb = Bs + (j * 256 + wave * 64) * 8;
      __builtin_amdgcn_global_load_lds((AS1 void*)ga, (AS3 void*)la, 16, 0, 0);
      __builtin_amdgcn_global_load_lds((AS1 void*)gb, (AS3 void*)lb, 16, 0, 0);
    }
    __syncthreads();

    // ---- LDS -> frags: A/B operand layout [m|n = lane&15][k = quad*8+j] ----
    short8 af[4], bf[4];
#pragma unroll
    for (int mi = 0; mi < 4; ++mi) {
      const int r = wm * 64 + mi * 16 + l15;
      af[mi] = *reinterpret_cast<const short8*>(As + r * 32 + quad * 8);
    }
#pragma unroll
    for (int ni = 0; ni < 4; ++ni) {
      const int r = wn * 64 + ni * 16 + l15;
      bf[ni] = *reinterpret_cast<const short8*>(Bs + r * 32 + quad * 8);
    }

#pragma unroll
    for (int mi = 0; mi < 4; ++mi)
#pragma unroll
      for (int ni = 0; ni < 4; ++ni)
        acc[mi][ni] = __builtin_amdgcn_mfma_f32_16x16x32_bf16(
            af[mi], bf[ni], acc[mi][ni], 0, 0, 0);
    __syncthreads();
  }

  // ---- epilogue: C/D layout col=lane&15, row=quad*4+reg; fp32 out ----
  float bv[4];
  int   cols[4];
#pragma unroll
  for (int ni = 0; ni < 4; ++ni) {
    cols[ni] = n0 + wn * 64 + ni * 16 + l15;
    bv[ni] = bias[cols[ni]];
  }
#pragma unroll
  for (int mi = 0; mi < 4; ++mi) {
#pragma unroll
    for (int r = 0; r < 4; ++r) {
      const int grow = m0 + wm * 64 + mi * 16 + quad * 4 + r;
      float* crow = C + (size_t)grow * N_DIM;
#pragma unroll
      for (int ni = 0; ni < 4; ++ni) {
        crow[cols[ni]] = acc[mi][ni][r] + bv[ni];
      }
    }
  }
}

extern "C" void kernel_launch(void* const* d_in, const int* in_sizes, int n_in,
                              void* d_out, int out_size, void* d_ws, size_t ws_size,
                              hipStream_t stream) {
  const float* x    = (const float*)d_in[0];   // fp32 (4,2048,4096)
  const float* circ = (const float*)d_in[1];   // fp32 (512,512,8)
  const float* bias = (const float*)d_in[2];   // fp32 (4096)
  float* out = (float*)d_out;                  // fp32 (4,2048,4096)

  // workspace layout: [0,32MB) bf16 W ; [32MB, 96MB) bf16 Xb
  unsigned short* W  = (unsigned short*)d_ws;
  unsigned short* Xb = (unsigned short*)((char*)d_ws + (size_t)N_DIM * K_DIM * 2);

  // 1) convert activations fp32 -> bf16
  convert_x_kernel<<<(M_DIM * K_DIM / 8) / 256, 256, 0, stream>>>(x, Xb);

  // 2) materialize dense circulant weight matrix (bf16) into workspace
  expand_w_kernel<<<(N_DIM * NB) / 256, 256, 0, stream>>>(circ, W);

  // 3) GEMM: out(M,N) = Xb(M,K) * W(N,K)^T + bias
  dim3 grid(N_DIM / 128, M_DIM / 128);  // (32, 64)
  gemm_bt_kernel<<<grid, 256, 0, stream>>>(Xb, W, bias, out);
}

// Round 4
// 389.094 us; speedup vs baseline: 1.3662x; 1.3662x over previous
//
#include <hip/hip_runtime.h>

#define AS1 __attribute__((address_space(1)))
#define AS3 __attribute__((address_space(3)))

typedef __attribute__((ext_vector_type(8))) short short8;        // 8 bf16 raw (4 VGPRs) — MFMA A/B frag
typedef __attribute__((ext_vector_type(4))) float floatx4;       // MFMA C/D frag
typedef __attribute__((ext_vector_type(8))) unsigned short u16x8;
typedef __attribute__((ext_vector_type(4))) unsigned short u16x4;
typedef __attribute__((ext_vector_type(4))) float f32x4;

#define M_DIM 8192   // B*S = 4*2048
#define K_DIM 4096   // IN_F
#define N_DIM 4096   // OUT_F
#define NB    512    // blocks along in/out feature dims
// BLK = 8, rfft comps: f0(real), f1,f2,f3(complex), f4(real)

#define SQ2H 0.70710678118654752f

// Xfreq / Ofreq plane offsets (bf16 elements), total 33,554,432 elems = 64 MB
#define P0_OFF 0           // [8192][512]  f0 (real)
#define P1_OFF 4194304     // [8192][1024] f1 (re,im interleaved k=2i,2i+1)
#define P2_OFF 12582912    // [8192][1024] f2
#define P3_OFF 20971520    // [8192][1024] f3
#define P4_OFF 29360128    // [8192][512]  f4 (real)
// Wfreq plane offsets (bf16 elements), total 3,670,016 elems = 7 MB
#define Q0_OFF 0           // [512][512]
#define Q1_OFF 262144      // [1024][1024] rows 0..511: (B1r,-B1i); rows 512..1023: (B1i,B1r)
#define Q2_OFF 1310720
#define Q3_OFF 2359296
#define Q4_OFF 3407872     // [512][512]

// fp32 -> bf16 raw bits, round-to-nearest-even (finite inputs only).
static __device__ __forceinline__ unsigned short f32_to_bf16(float f) {
  union { float f; unsigned int u; } v;
  v.f = f;
  return (unsigned short)((v.u + 0x7FFFu + ((v.u >> 16) & 1u)) >> 16);
}
static __device__ __forceinline__ float bf16_to_f32(unsigned short h) {
  union { unsigned int u; float f; } v;
  v.u = ((unsigned int)h) << 16;
  return v.f;
}

// length-8 real FFT comps from 8 reals
struct F8 { float a0, a4, r1, i1, r2, i2, r3, i3; };
static __device__ __forceinline__ F8 rfft8(const float* x) {
  F8 o;
  o.a0 = x[0]+x[1]+x[2]+x[3]+x[4]+x[5]+x[6]+x[7];
  o.a4 = x[0]-x[1]+x[2]-x[3]+x[4]-x[5]+x[6]-x[7];
  const float d1 = x[1]-x[3]-x[5]+x[7];   // for r1/r3
  const float s1 = x[1]+x[3]-x[5]-x[7];   // for i1/i3
  o.r1 = x[0]-x[4] + SQ2H*d1;
  o.i1 = -(SQ2H*s1 + x[2]-x[6]);
  o.r2 = x[0]-x[2]+x[4]-x[6];
  o.i2 = -(x[1]-x[3]+x[5]-x[7]);
  o.r3 = x[0]-x[4] - SQ2H*d1;
  o.i3 = -(SQ2H*s1 - x[2]+x[6]);
  return o;
}

// ===========================================================================
// NEW PATH: frequency-domain (5 small GEMMs, 4.9x fewer FLOPs)
// ===========================================================================

// ---- x (fp32, row-major (8192,4096)) -> Xfreq planes (bf16) ----
__global__ __launch_bounds__(256) void xtransform_kernel(
    const float* __restrict__ x, unsigned short* __restrict__ XF)
{
  const int tid = blockIdx.x * 256 + threadIdx.x;   // 0 .. 8192*512-1
  const int m = tid >> 9;
  const int i = tid & 511;
  float v[8];
  *reinterpret_cast<f32x4*>(v)     = *reinterpret_cast<const f32x4*>(x + (size_t)tid * 8);
  *reinterpret_cast<f32x4*>(v + 4) = *reinterpret_cast<const f32x4*>(x + (size_t)tid * 8 + 4);
  F8 f = rfft8(v);
  XF[P0_OFF + (size_t)m * 512 + i] = f32_to_bf16(f.a0);
  XF[P4_OFF + (size_t)m * 512 + i] = f32_to_bf16(f.a4);
  unsigned int p1 = (unsigned int)f32_to_bf16(f.r1) | ((unsigned int)f32_to_bf16(f.i1) << 16);
  unsigned int p2 = (unsigned int)f32_to_bf16(f.r2) | ((unsigned int)f32_to_bf16(f.i2) << 16);
  unsigned int p3 = (unsigned int)f32_to_bf16(f.r3) | ((unsigned int)f32_to_bf16(f.i3) << 16);
  *reinterpret_cast<unsigned int*>(XF + P1_OFF + (size_t)m * 1024 + 2 * i) = p1;
  *reinterpret_cast<unsigned int*>(XF + P2_OFF + (size_t)m * 1024 + 2 * i) = p2;
  *reinterpret_cast<unsigned int*>(XF + P3_OFF + (size_t)m * 1024 + 2 * i) = p3;
}

// ---- circ (fp32 (512,512,8)) -> Wfreq planes (bf16) ----
__global__ __launch_bounds__(256) void wtransform_kernel(
    const float* __restrict__ c, unsigned short* __restrict__ WF)
{
  const int tid = blockIdx.x * 256 + threadIdx.x;   // 0 .. 512*512-1
  const int n = tid >> 9;   // output block
  const int i = tid & 511;  // input block
  float v[8];
  *reinterpret_cast<f32x4*>(v)     = *reinterpret_cast<const f32x4*>(c + (size_t)tid * 8);
  *reinterpret_cast<f32x4*>(v + 4) = *reinterpret_cast<const f32x4*>(c + (size_t)tid * 8 + 4);
  F8 f = rfft8(v);
  WF[Q0_OFF + (size_t)n * 512 + i] = f32_to_bf16(f.a0);
  WF[Q4_OFF + (size_t)n * 512 + i] = f32_to_bf16(f.a4);
  // Or rows (n): k=2i -> Br, k=2i+1 -> -Bi ; Oi rows (512+n): k=2i -> Bi, k=2i+1 -> Br
  unsigned int q1or = (unsigned int)f32_to_bf16(f.r1) | ((unsigned int)f32_to_bf16(-f.i1) << 16);
  unsigned int q1oi = (unsigned int)f32_to_bf16(f.i1) | ((unsigned int)f32_to_bf16(f.r1) << 16);
  unsigned int q2or = (unsigned int)f32_to_bf16(f.r2) | ((unsigned int)f32_to_bf16(-f.i2) << 16);
  unsigned int q2oi = (unsigned int)f32_to_bf16(f.i2) | ((unsigned int)f32_to_bf16(f.r2) << 16);
  unsigned int q3or = (unsigned int)f32_to_bf16(f.r3) | ((unsigned int)f32_to_bf16(-f.i3) << 16);
  unsigned int q3oi = (unsigned int)f32_to_bf16(f.i3) | ((unsigned int)f32_to_bf16(f.r3) << 16);
  *reinterpret_cast<unsigned int*>(WF + Q1_OFF + (size_t)n * 1024 + 2 * i)         = q1or;
  *reinterpret_cast<unsigned int*>(WF + Q1_OFF + (size_t)(512 + n) * 1024 + 2 * i) = q1oi;
  *reinterpret_cast<unsigned int*>(WF + Q2_OFF + (size_t)n * 1024 + 2 * i)         = q2or;
  *reinterpret_cast<unsigned int*>(WF + Q2_OFF + (size_t)(512 + n) * 1024 + 2 * i) = q2oi;
  *reinterpret_cast<unsigned int*>(WF + Q3_OFF + (size_t)n * 1024 + 2 * i)         = q3or;
  *reinterpret_cast<unsigned int*>(WF + Q3_OFF + (size_t)(512 + n) * 1024 + 2 * i) = q3oi;
}

// ---- per-frequency GEMM: O_z(M,Nz) = X_z(M,Kz) * W_z(Nz,Kz)^T, bf16 ----
// m97 structure: 128x128 tile, BK=32, 4 waves 2x2, 4x4 16x16x32 MFMA frags.
__global__ __launch_bounds__(256) void gemm_freq_kernel(
    const unsigned short* __restrict__ XF,
    const unsigned short* __restrict__ WF,
    unsigned short* __restrict__ OF)
{
  int K, aoff, boff;  // N == K for every plane; O plane offset == A plane offset
  switch (blockIdx.z) {
    case 0:  K = 512;  aoff = P0_OFF; boff = Q0_OFF; break;
    case 1:  K = 1024; aoff = P1_OFF; boff = Q1_OFF; break;
    case 2:  K = 1024; aoff = P2_OFF; boff = Q2_OFF; break;
    case 3:  K = 1024; aoff = P3_OFF; boff = Q3_OFF; break;
    default: K = 512;  aoff = P4_OFF; boff = Q4_OFF; break;
  }
  const int n0 = blockIdx.x * 128;
  if (n0 >= K) return;  // z=0/4 only have N=512 (grid.x covers 1024)
  const int m0 = blockIdx.y * 128;

  const unsigned short* A  = XF + aoff;
  const unsigned short* Bm = WF + boff;
  unsigned short* C        = OF + aoff;

  __shared__ alignas(16) unsigned short As[128 * 32];
  __shared__ alignas(16) unsigned short Bs[128 * 32];

  const int tid  = threadIdx.x;
  const int lane = tid & 63;
  const int wave = tid >> 6;
  const int wm   = wave >> 1;
  const int wn   = wave & 1;
  const int quad = lane >> 4;
  const int l15  = lane & 15;

  floatx4 acc[4][4];
#pragma unroll
  for (int i = 0; i < 4; ++i)
#pragma unroll
    for (int j = 0; j < 4; ++j) acc[i][j] = (floatx4){0.f, 0.f, 0.f, 0.f};

  for (int k0 = 0; k0 < K; k0 += 32) {
#pragma unroll
    for (int j = 0; j < 2; ++j) {
      const int chunk = j * 256 + wave * 64 + lane;
      const int row   = chunk >> 2;
      const int kc    = (chunk & 3) << 3;
      const unsigned short* ga = A  + (size_t)(m0 + row) * K + (k0 + kc);
      const unsigned short* gb = Bm + (size_t)(n0 + row) * K + (k0 + kc);
      unsigned short* la = As + (j * 256 + wave * 64) * 8;
      unsigned short* lb = Bs + (j * 256 + wave * 64) * 8;
      __builtin_amdgcn_global_load_lds((AS1 void*)ga, (AS3 void*)la, 16, 0, 0);
      __builtin_amdgcn_global_load_lds((AS1 void*)gb, (AS3 void*)lb, 16, 0, 0);
    }
    __syncthreads();

    short8 af[4], bf[4];
#pragma unroll
    for (int mi = 0; mi < 4; ++mi)
      af[mi] = *reinterpret_cast<const short8*>(As + (wm * 64 + mi * 16 + l15) * 32 + quad * 8);
#pragma unroll
    for (int ni = 0; ni < 4; ++ni)
      bf[ni] = *reinterpret_cast<const short8*>(Bs + (wn * 64 + ni * 16 + l15) * 32 + quad * 8);

#pragma unroll
    for (int mi = 0; mi < 4; ++mi)
#pragma unroll
      for (int ni = 0; ni < 4; ++ni)
        acc[mi][ni] = __builtin_amdgcn_mfma_f32_16x16x32_bf16(
            af[mi], bf[ni], acc[mi][ni], 0, 0, 0);
    __syncthreads();
  }

  // epilogue: C/D layout col=lane&15, row=quad*4+reg; bf16 store
#pragma unroll
  for (int mi = 0; mi < 4; ++mi) {
#pragma unroll
    for (int r = 0; r < 4; ++r) {
      const int grow = m0 + wm * 64 + mi * 16 + quad * 4 + r;
      unsigned short* crow = C + (size_t)grow * K;
#pragma unroll
      for (int ni = 0; ni < 4; ++ni)
        crow[n0 + wn * 64 + ni * 16 + l15] = f32_to_bf16(acc[mi][ni][r]);
    }
  }
}

// ---- irfft + bias: Ofreq planes (bf16) -> out (fp32 (8192,4096)) ----
// thread handles (m, 4 consecutive output blocks)
__global__ __launch_bounds__(256) void irfft_kernel(
    const unsigned short* __restrict__ OF,
    const float* __restrict__ bias,
    float* __restrict__ out)
{
  const int tid = blockIdx.x * 256 + threadIdx.x;  // 0 .. 8192*128-1
  const int m   = tid >> 7;
  const int nb4 = tid & 127;                       // blocks nb4*4 .. +3

  const u16x4 a0v = *reinterpret_cast<const u16x4*>(OF + P0_OFF + (size_t)m * 512 + nb4 * 4);
  const u16x4 a4v = *reinterpret_cast<const u16x4*>(OF + P4_OFF + (size_t)m * 512 + nb4 * 4);
  const u16x4 r1v = *reinterpret_cast<const u16x4*>(OF + P1_OFF + (size_t)m * 1024 + nb4 * 4);
  const u16x4 i1v = *reinterpret_cast<const u16x4*>(OF + P1_OFF + (size_t)m * 1024 + 512 + nb4 * 4);
  const u16x4 r2v = *reinterpret_cast<const u16x4*>(OF + P2_OFF + (size_t)m * 1024 + nb4 * 4);
  const u16x4 i2v = *reinterpret_cast<const u16x4*>(OF + P2_OFF + (size_t)m * 1024 + 512 + nb4 * 4);
  const u16x4 r3v = *reinterpret_cast<const u16x4*>(OF + P3_OFF + (size_t)m * 1024 + nb4 * 4);
  const u16x4 i3v = *reinterpret_cast<const u16x4*>(OF + P3_OFF + (size_t)m * 1024 + 512 + nb4 * 4);

#pragma unroll
  for (int j = 0; j < 4; ++j) {
    const int nblk = nb4 * 4 + j;
    const float a0 = bf16_to_f32(a0v[j]), a4 = bf16_to_f32(a4v[j]);
    const float r1 = bf16_to_f32(r1v[j]), i1 = bf16_to_f32(i1v[j]);
    const float r2 = bf16_to_f32(r2v[j]), i2 = bf16_to_f32(i2v[j]);
    const float r3 = bf16_to_f32(r3v[j]), i3 = bf16_to_f32(i3v[j]);

    const float ep = a0 + a4, em = a0 - a4;
    const float sr1 = SQ2H * r1, si1 = SQ2H * i1;
    const float sr3 = SQ2H * r3, si3 = SQ2H * i3;
    float o[8];
    o[0] = (ep + 2.f * ( r1 + r2 + r3)) * 0.125f;
    o[1] = (em + 2.f * ( sr1 - si1 - i2 - sr3 - si3)) * 0.125f;
    o[2] = (ep + 2.f * (-i1 - r2 + i3)) * 0.125f;
    o[3] = (em + 2.f * (-sr1 - si1 + i2 + sr3 - si3)) * 0.125f;
    o[4] = (ep + 2.f * (-r1 + r2 - r3)) * 0.125f;
    o[5] = (em + 2.f * (-sr1 + si1 - i2 + sr3 + si3)) * 0.125f;
    o[6] = (ep + 2.f * ( i1 - r2 - i3)) * 0.125f;
    o[7] = (em + 2.f * ( sr1 + si1 + i2 - sr3 + si3)) * 0.125f;

    const float* bs = bias + nblk * 8;
    f32x4 lo, hi;
#pragma unroll
    for (int t = 0; t < 4; ++t) { lo[t] = o[t] + bs[t]; hi[t] = o[t + 4] + bs[t + 4]; }
    float* dst = out + (size_t)m * N_DIM + nblk * 8;
    *reinterpret_cast<f32x4*>(dst)     = lo;
    *reinterpret_cast<f32x4*>(dst + 4) = hi;
  }
}

// ===========================================================================
// FALLBACK PATH (round-3, passing): dense W expansion + one big GEMM
// ===========================================================================

__global__ __launch_bounds__(256) void convert_x_kernel(
    const float* __restrict__ x, unsigned short* __restrict__ Xb)
{
  const size_t t = (size_t)blockIdx.x * 256 + threadIdx.x;
  const f32x4 a = *reinterpret_cast<const f32x4*>(x + t * 8);
  const f32x4 b = *reinterpret_cast<const f32x4*>(x + t * 8 + 4);
  union { u16x8 v; unsigned short s[8]; } o;
#pragma unroll
  for (int u = 0; u < 4; ++u) { o.s[u] = f32_to_bf16(a[u]); o.s[u + 4] = f32_to_bf16(b[u]); }
  *reinterpret_cast<u16x8*>(Xb + t * 8) = o.v;
}

__global__ __launch_bounds__(256) void expand_w_kernel(
    const float* __restrict__ c, unsigned short* __restrict__ W)
{
  const int tid = blockIdx.x * 256 + threadIdx.x;
  const int o = tid >> 9, i = tid & 511, n = o >> 3, t = o & 7;
  const float* src = c + ((size_t)(n * NB + i) << 3);
  float raw[8];
  *reinterpret_cast<f32x4*>(raw)     = *reinterpret_cast<const f32x4*>(src);
  *reinterpret_cast<f32x4*>(raw + 4) = *reinterpret_cast<const f32x4*>(src + 4);
  union { u16x8 v; unsigned short s[8]; } outv;
#pragma unroll
  for (int u = 0; u < 8; ++u) outv.s[u] = f32_to_bf16(raw[(t - u) & 7]);
  *reinterpret_cast<u16x8*>(W + (size_t)o * K_DIM + i * 8) = outv.v;
}

__global__ __launch_bounds__(256) void gemm_bt_kernel(
    const unsigned short* __restrict__ A, const unsigned short* __restrict__ Bm,
    const float* __restrict__ bias, float* __restrict__ C)
{
  __shared__ alignas(16) unsigned short As[128 * 32];
  __shared__ alignas(16) unsigned short Bs[128 * 32];
  const int tid = threadIdx.x, lane = tid & 63, wave = tid >> 6;
  const int wm = wave >> 1, wn = wave & 1;
  const int m0 = blockIdx.y * 128, n0 = blockIdx.x * 128;
  const int quad = lane >> 4, l15 = lane & 15;

  floatx4 acc[4][4];
#pragma unroll
  for (int i = 0; i < 4; ++i)
#pragma unroll
    for (int j = 0; j < 4; ++j) acc[i][j] = (floatx4){0.f, 0.f, 0.f, 0.f};

  for (int k0 = 0; k0 < K_DIM; k0 += 32) {
#pragma unroll
    for (int j = 0; j < 2; ++j) {
      const int chunk = j * 256 + wave * 64 + lane;
      const int row = chunk >> 2, kc = (chunk & 3) << 3;
      const unsigned short* ga = A  + (size_t)(m0 + row) * K_DIM + (k0 + kc);
      const unsigned short* gb = Bm + (size_t)(n0 + row) * K_DIM + (k0 + kc);
      unsigned short* la = As + (j * 256 + wave * 64) * 8;
      unsigned short* lb = Bs + (j * 256 + wave * 64) * 8;
      __builtin_amdgcn_global_load_lds((AS1 void*)ga, (AS3 void*)la, 16, 0, 0);
      __builtin_amdgcn_global_load_lds((AS1 void*)gb, (AS3 void*)lb, 16, 0, 0);
    }
    __syncthreads();
    short8 af[4], bf[4];
#pragma unroll
    for (int mi = 0; mi < 4; ++mi)
      af[mi] = *reinterpret_cast<const short8*>(As + (wm * 64 + mi * 16 + l15) * 32 + quad * 8);
#pragma unroll
    for (int ni = 0; ni < 4; ++ni)
      bf[ni] = *reinterpret_cast<const short8*>(Bs + (wn * 64 + ni * 16 + l15) * 32 + quad * 8);
#pragma unroll
    for (int mi = 0; mi < 4; ++mi)
#pragma unroll
      for (int ni = 0; ni < 4; ++ni)
        acc[mi][ni] = __builtin_amdgcn_mfma_f32_16x16x32_bf16(af[mi], bf[ni], acc[mi][ni], 0, 0, 0);
    __syncthreads();
  }
  float bv[4]; int cols[4];
#pragma unroll
  for (int ni = 0; ni < 4; ++ni) { cols[ni] = n0 + wn * 64 + ni * 16 + l15; bv[ni] = bias[cols[ni]]; }
#pragma unroll
  for (int mi = 0; mi < 4; ++mi)
#pragma unroll
    for (int r = 0; r < 4; ++r) {
      const int grow = m0 + wm * 64 + mi * 16 + quad * 4 + r;
      float* crow = C + (size_t)grow * N_DIM;
#pragma unroll
      for (int ni = 0; ni < 4; ++ni) crow[cols[ni]] = acc[mi][ni][r] + bv[ni];
    }
}

extern "C" void kernel_launch(void* const* d_in, const int* in_sizes, int n_in,
                              void* d_out, int out_size, void* d_ws, size_t ws_size,
                              hipStream_t stream) {
  const float* x    = (const float*)d_in[0];
  const float* circ = (const float*)d_in[1];
  const float* bias = (const float*)d_in[2];
  float* out = (float*)d_out;

  // freq-domain ws layout: XF bf16 64MB | WF bf16 7MB | OF bf16 64MB
  const size_t XF_BYTES = (size_t)33554432 * 2;
  const size_t WF_BYTES = (size_t)3670016 * 2;
  const size_t OF_BYTES = (size_t)33554432 * 2;
  const size_t NEED = XF_BYTES + WF_BYTES + OF_BYTES;  // 141,557,760 B

  if (ws_size >= NEED) {
    unsigned short* XF = (unsigned short*)d_ws;
    unsigned short* WF = (unsigned short*)((char*)d_ws + XF_BYTES);
    unsigned short* OF = (unsigned short*)((char*)d_ws + XF_BYTES + WF_BYTES);

    wtransform_kernel<<<(NB * NB) / 256, 256, 0, stream>>>(circ, WF);
    xtransform_kernel<<<(M_DIM * NB) / 256, 256, 0, stream>>>(x, XF);
    dim3 grid(8, M_DIM / 128, 5);  // n-tiles (max N=1024), m-tiles, freqs
    gemm_freq_kernel<<<grid, 256, 0, stream>>>(XF, WF, OF);
    irfft_kernel<<<(M_DIM * 128) / 256, 256, 0, stream>>>(OF, bias, out);
  } else {
    // fallback: dense GEMM path (96 MB ws)
    unsigned short* W  = (unsigned short*)d_ws;
    unsigned short* Xb = (unsigned short*)((char*)d_ws + (size_t)N_DIM * K_DIM * 2);
    convert_x_kernel<<<(M_DIM * K_DIM / 8) / 256, 256, 0, stream>>>(x, Xb);
    expand_w_kernel<<<(N_DIM * NB) / 256, 256, 0, stream>>>(circ, W);
    dim3 grid(N_DIM / 128, M_DIM / 128);
    gemm_bt_kernel<<<grid, 256, 0, stream>>>(Xb, W, bias, out);
  }
}